// Round 7
// baseline (45.325 us; speedup 1.0000x reference)
//
#include <hip/hip_runtime.h>

#define NBOX 4096
#define MAXDET 100
#define KSEL 192     // exact top-K target (>= 100 + NMS-suppressed margin)
#define SL 8         // producer slices (blocks) per image
#define TPB 256      // threads per block (4 waves)
#define WPB 4        // waves per block

typedef unsigned long long u64;
typedef unsigned int u32;

__device__ __forceinline__ float iou_xyxy(float4 a, float4 c) {
  float aa = fmaxf(a.z - a.x, 0.f) * fmaxf(a.w - a.y, 0.f);
  float ca = fmaxf(c.z - c.x, 0.f) * fmaxf(c.w - c.y, 0.f);
  float w = fmaxf(fminf(a.z, c.z) - fmaxf(a.x, c.x), 0.f);
  float h = fmaxf(fminf(a.w, c.w) - fmaxf(a.y, c.y), 0.f);
  float inter = w * h;
  return inter / fmaxf(aa + ca - inter, 1e-9f);
}

// One bitonic compare-exchange level over R*64 register-resident u64 keys.
template <int R>
__device__ __forceinline__ void merge_step(u64 (&v)[R], int lane, int k, int j) {
  if (j >= 64) {
    int jj = j >> 6;
#pragma unroll
    for (int r = 0; r < R; ++r)
      if (!(r & jj)) {
        int r2 = r | jj;
        bool up = ((r & (k >> 6)) != 0);
        u64 a = v[r], c = v[r2];
        if (up ? (a > c) : (a < c)) { v[r] = c; v[r2] = a; }
      }
  } else {
#pragma unroll
    for (int r = 0; r < R; ++r) {
      u64 a = v[r];
      u64 o = __shfl_xor(a, j);
      bool up = (k >= 64) ? ((r & (k >> 6)) != 0) : ((lane & k) != 0);
      bool is_lower = ((lane & j) == 0);
      bool keep_max = up ^ is_lower;
      v[r] = keep_max ? (a > o ? a : o) : (a < o ? a : o);
    }
  }
}

// Full descending bitonic sort of R*64 register keys (one wave, barrier-free).
template <int R>
__device__ __forceinline__ void sort_regs_desc(u64 (&v)[R], int lane) {
  const int S = R * 64;
  for (int k = 2; k <= S; k <<= 1)
    for (int j = k >> 1; j > 0; j >>= 1) merge_step<R>(v, lane, k, j);
}

// Merge two desc-sorted KSEL lists (zero-padded to 256) -> desc top-KSEL to dst.
// Returns count of nonzero (valid) keys among the kept KSEL (wave-uniform).
__device__ __forceinline__ int merge_lists(const u64* A, const u64* Bp,
                                           u64* dst, int lane) {
  u64 m[8];
#pragma unroll
  for (int r = 0; r < 4; ++r) {
    int i = r * 64 + lane;
    m[r] = (i < KSEL) ? A[i] : 0ull;
  }
#pragma unroll
  for (int r = 0; r < 4; ++r) {
    int i = 255 - (r * 64 + lane);  // reversed (ascending) second half
    m[4 + r] = (i < KSEL) ? Bp[i] : 0ull;
  }
  for (int j = 256; j > 0; j >>= 1) merge_step<8>(m, lane, 1024, j);
  int c = (int)__popcll(__ballot(m[0] != 0ull)) +
          (int)__popcll(__ballot(m[1] != 0ull)) +
          (int)__popcll(__ballot(m[2] != 0ull));
#pragma unroll
  for (int r = 0; r < 3; ++r) dst[r * 64 + lane] = m[r];
  return c;
}

// Chunked greedy NMS over sorted (descending) keys in LDS; boxes from global.
__device__ void run_nms(const u64* keys, int len, const float4* __restrict__ bx,
                        float4* chbox, u64* srow, u64* keptkey, float4* keptbox,
                        u64* crossMask, int* p_kept, int tid, int nslice) {
  for (int base = 0; base < len; base += 64) {
    if (*p_kept >= MAXDET) break;  // uniform (written before a barrier)
    int L = min(64, len - base);
    if (tid < 64) {  // stage chunk boxes (xyxy)
      if (tid == 0) *crossMask = 0ull;
      float4 bb = make_float4(0.f, 0.f, 0.f, 0.f);
      if (tid < L) {
        u64 k = keys[base + tid];
        int orig = NBOX - 1 - (int)(k & 0xFFFFFFFFull);
        float4 c = bx[orig];
        bb = make_float4(c.x - 0.5f * c.z, c.y - 0.5f * c.w,
                         c.x + 0.5f * c.z, c.y + 0.5f * c.w);
      }
      chbox[tid] = bb;
      srow[tid] = 0ull;
    }
    __syncthreads();
    int kept0 = *p_kept;
    {  // parallel pair tests: 64 boxes x nslice slices
      int i = tid & 63, slice = tid >> 6;
      if (i < L) {
        float4 a = chbox[i];
        bool hit = false;
        for (int k0 = slice; k0 < kept0 && !hit; k0 += nslice)
          if (iou_xyxy(a, keptbox[k0]) > 0.7f) hit = true;
        if (hit) atomicOr(crossMask, 1ull << i);
        u64 bits = 0ull;
        for (int j = i + 1 + slice; j < L; j += nslice)
          if (iou_xyxy(a, chbox[j]) > 0.7f) bits |= 1ull << j;
        if (bits) atomicOr(&srow[i], bits);
      }
    }
    __syncthreads();
    if (tid < 64) {  // greedy scan: sparse fast path, exact serial fallback
      u64 removed = *crossMask;
      if (L < 64) removed |= ~((1ull << L) - 1ull);
      u64 K = ~removed;
      u64 myrow = srow[tid];
      u64 contrib = ((K >> tid) & 1ull) ? (myrow & K) : 0ull;
#pragma unroll
      for (int d = 1; d < 64; d <<= 1) contrib |= __shfl_xor(contrib, d);
      u64 keepm;
      if (contrib == 0ull) {
        keepm = K;
      } else {
        u64 removed2 = removed;
        keepm = 0ull;
        for (int ii = 0; ii < L; ++ii) {
          u64 row = __shfl(myrow, ii);
          if (!((removed2 >> ii) & 1ull)) {
            keepm |= 1ull << ii;
            removed2 |= row;
          }
        }
      }
      if ((keepm >> tid) & 1ull) {
        int pos = kept0 + __popcll(keepm & ((1ull << tid) - 1ull));
        if (pos < MAXDET) {
          keptkey[pos] = keys[base + tid];
          keptbox[pos] = chbox[tid];
        }
      }
      if (tid == 0) *p_kept = min(MAXDET, kept0 + __popcll(keepm));
    }
    __syncthreads();
  }
}

// ---------------- Fused multi-CU kernel with device spin barrier ----------------
__global__ __launch_bounds__(TPB) void pp_fused(
    const float* __restrict__ boxes, const float* __restrict__ scores,
    float* __restrict__ out, u32* __restrict__ ctr, u64* __restrict__ lists,
    int B) {
  const int bid = blockIdx.x;
  const int img = bid >> 3, slice = bid & (SL - 1);
  const int tid = threadIdx.x, wid = tid >> 6, lane = tid & 63;
  const u32 target = (u32)(B * SL);

  __shared__ u64 wlist[WPB][128];
  __shared__ u64 blist[2][KSEL];
  __shared__ u64 lA[SL][KSEL];
  __shared__ u64 lB2[4][KSEL];
  __shared__ u64 lC[2][KSEL];
  __shared__ u64 cand[KSEL];
  __shared__ u64 skey[NBOX];  // fallback full sort only
  __shared__ float4 chbox[64];
  __shared__ u64 srow[64];
  __shared__ float4 keptbox[MAXDET];
  __shared__ u64 keptkey[MAXDET];
  __shared__ u64 crossMask;
  __shared__ int s_kept, s_C, s_M;

  const float* sc = scores + (size_t)img * NBOX;
  const float4* bx = (const float4*)boxes + (size_t)img * NBOX;

  // ---- Phase A: slice top-192 (all blocks) ----
  {
    u64 v[2];
    int base_n = slice * 512 + wid * 128;
#pragma unroll
    for (int r = 0; r < 2; ++r) {
      int n = base_n + r * 64 + lane;
      float x = sc[n];
      v[r] = (x > 0.5f)
                 ? ((((u64)__float_as_uint(x)) << 32) | (u64)(u32)(NBOX - 1 - n))
                 : 0ull;
    }
    sort_regs_desc<2>(v, lane);  // 28 shfl levels, barrier-free
    wlist[wid][lane] = v[0];
    wlist[wid][64 + lane] = v[1];
  }
  __syncthreads();
  if (wid < 2) {  // merge 128+128 -> 256, keep top 192
    u64 m[4];
    const u64* A = wlist[2 * wid];
    const u64* Bl = wlist[2 * wid + 1];
    m[0] = A[lane]; m[1] = A[64 + lane];
    m[2] = Bl[127 - lane]; m[3] = Bl[63 - lane];
    for (int j = 128; j > 0; j >>= 1) merge_step<4>(m, lane, 512, j);
    blist[wid][lane] = m[0];
    blist[wid][64 + lane] = m[1];
    blist[wid][128 + lane] = m[2];
  }
  __syncthreads();
  if (wid == 0) {  // merge 192+192 -> slice top-192, write to global
    u64* dst = lists + ((size_t)img * SL + slice) * KSEL;
    merge_lists(blist[0], blist[1], dst, lane);
  }
  __threadfence();  // make list writes visible device-wide
  __syncthreads();
  if (tid == 0)
    __hip_atomic_fetch_add(ctr, 1u, __ATOMIC_ACQ_REL, __HIP_MEMORY_SCOPE_AGENT);
  if (slice != 0) return;  // producers done

  // ---- Barrier wait (consumer blocks, one per image) ----
  if (tid == 0) {
    s_kept = 0;
    long long it = 0;
    while (__hip_atomic_load(ctr, __ATOMIC_ACQUIRE, __HIP_MEMORY_SCOPE_AGENT) <
           target) {
      __builtin_amdgcn_s_sleep(2);
      if (++it > (64LL << 20)) break;  // safety valve: never hang
    }
  }
  __syncthreads();
  __threadfence();

  // ---- Phase B: merge 8 slice lists -> exact image top-192 ----
  {
    const u64* src = lists + (size_t)img * SL * KSEL;
    for (int i = tid; i < SL * KSEL; i += TPB) ((u64*)lA)[i] = src[i];
  }
  __syncthreads();
  if (wid < 4) merge_lists(lA[2 * wid], lA[2 * wid + 1], lB2[wid], lane);
  __syncthreads();
  if (wid < 2) merge_lists(lB2[2 * wid], lB2[2 * wid + 1], lC[wid], lane);
  __syncthreads();
  if (wid == 0) {
    int c = merge_lists(lC[0], lC[1], cand, lane);
    if (lane == 0) s_C = c;
  }
  __syncthreads();
  const int C = s_C;  // C < KSEL => cand holds ALL valid boxes of the image

  run_nms(cand, C, bx, chbox, srow, keptkey, keptbox, &crossMask, &s_kept, tid, WPB);

  // ---- Fallback (kept<100 while candidates were dropped) — not taken here ----
  const int kept1 = s_kept;
  const bool need_full = (kept1 < MAXDET) && (C == KSEL);
  __syncthreads();  // all reads of s_kept done before any rewrite
  if (need_full) {
    if (tid == 0) { s_kept = 0; s_M = 0; }
    __syncthreads();
    int wcnt = 0;
#pragma unroll
    for (int q = 0; q < NBOX / TPB; ++q) {
      int n = q * TPB + tid;
      float x = sc[n];
      bool valid = (x > 0.5f);
      u64 key = (u64)(u32)(NBOX - 1 - n);
      if (valid) key |= ((u64)__float_as_uint(x)) << 32;
      skey[n] = key;
      u64 bal = __ballot(valid);
      if (lane == 0) wcnt += (int)__popcll(bal);
    }
    if (lane == 0) atomicAdd(&s_M, wcnt);
    __syncthreads();
    const int M = s_M;
    for (int k = 2; k <= NBOX; k <<= 1)
      for (int j = k >> 1; j > 0; j >>= 1) {
        for (int t = tid; t < NBOX; t += TPB) {
          int ixj = t ^ j;
          if (ixj > t) {
            u64 a = skey[t], c2 = skey[ixj];
            bool up = (t & k) != 0;
            if (up ? (a > c2) : (a < c2)) { skey[t] = c2; skey[ixj] = a; }
          }
        }
        __syncthreads();
      }
    run_nms(skey, M, bx, chbox, srow, keptkey, keptbox, &crossMask, &s_kept, tid, WPB);
  }

  // ---- Outputs ----
  const int nk = s_kept;
  if (tid < MAXDET) {
    float v0 = 0.f, v1 = 0.f, v2 = 0.f, v3 = 0.f, v4 = 0.f;
    if (tid < nk) {
      u64 key = keptkey[tid];
      int orig = NBOX - 1 - (int)(key & 0xFFFFFFFFull);
      float4 bb = bx[orig];  // original cxcywh
      v0 = bb.x; v1 = bb.y; v2 = bb.z; v3 = bb.w;
      v4 = __uint_as_float((u32)(key >> 32));
    }
    float* o = out + ((size_t)img * MAXDET + tid) * 5;
    o[0] = v0; o[1] = v1; o[2] = v2; o[3] = v3; o[4] = v4;
  }
  if (tid == 0) out[(size_t)B * MAXDET * 5 + img] = (float)nk;
}

// ---------------- Monolithic fallback (only if ws too small) — R6 structure ----
#define MNT 1024
#define MNW 16
__global__ __launch_bounds__(MNT) void postproc_mono(
    const float* __restrict__ boxes, const float* __restrict__ scores,
    float* __restrict__ out, int B) {
  const int b = blockIdx.x;
  const int tid = threadIdx.x, wid = tid >> 6, lane = tid & 63;
  __shared__ u64 listA[MNW][KSEL];
  __shared__ u64 listB[8][KSEL];
  __shared__ u64 cand[KSEL];
  __shared__ u64 skey[NBOX];
  __shared__ float4 chbox[64];
  __shared__ u64 srow[64];
  __shared__ float4 keptbox[MAXDET];
  __shared__ u64 keptkey[MAXDET];
  __shared__ u64 crossMask;
  __shared__ int s_kept, s_C, s_M;

  const float* sc = scores + (size_t)b * NBOX;
  const float4* bx = (const float4*)boxes + (size_t)b * NBOX;
  if (tid == 0) { s_kept = 0; s_M = 0; }

  float sreg[4];
  u64 v[4];
#pragma unroll
  for (int q = 0; q < 4; ++q) {
    int i = wid * 256 + q * 64 + lane;
    float x = sc[i];
    sreg[q] = x;
    v[q] = (x > 0.5f)
               ? ((((u64)__float_as_uint(x)) << 32) | (u64)(u32)(NBOX - 1 - i))
               : 0ull;
  }
  sort_regs_desc<4>(v, lane);
#pragma unroll
  for (int r = 0; r < 3; ++r) listA[wid][r * 64 + lane] = v[r];
  __syncthreads();
  if (wid < 8) merge_lists(listA[2 * wid], listA[2 * wid + 1], listB[wid], lane);
  __syncthreads();
  if (wid < 4) merge_lists(listB[2 * wid], listB[2 * wid + 1], listA[wid], lane);
  __syncthreads();
  if (wid < 2) merge_lists(listA[2 * wid], listA[2 * wid + 1], listB[wid], lane);
  __syncthreads();
  if (wid == 0) {
    int c = merge_lists(listB[0], listB[1], cand, lane);
    if (lane == 0) s_C = c;
  }
  __syncthreads();
  const int C = s_C;
  run_nms(cand, C, bx, chbox, srow, keptkey, keptbox, &crossMask, &s_kept, tid, MNW);
  const int kept1 = s_kept;
  const bool need_full = (kept1 < MAXDET) && (C == KSEL);
  __syncthreads();
  if (need_full) {
    if (tid == 0) s_kept = 0;
    int wcnt = 0;
#pragma unroll
    for (int q = 0; q < 4; ++q) {
      int i = wid * 256 + q * 64 + lane;
      float x = sreg[q];
      bool valid = (x > 0.5f);
      u64 key = (u64)(u32)(NBOX - 1 - i);
      if (valid) key |= ((u64)__float_as_uint(x)) << 32;
      skey[i] = key;
      u64 bal = __ballot(valid);
      if (lane == 0) wcnt += (int)__popcll(bal);
    }
    if (lane == 0) atomicAdd(&s_M, wcnt);
    __syncthreads();
    const int M = s_M;
    for (int k = 2; k <= NBOX; k <<= 1)
      for (int j = k >> 1; j > 0; j >>= 1) {
        for (int t = tid; t < NBOX; t += MNT) {
          int ixj = t ^ j;
          if (ixj > t) {
            u64 a = skey[t], c2 = skey[ixj];
            bool up = (t & k) != 0;
            if (up ? (a > c2) : (a < c2)) { skey[t] = c2; skey[ixj] = a; }
          }
        }
        __syncthreads();
      }
    run_nms(skey, M, bx, chbox, srow, keptkey, keptbox, &crossMask, &s_kept, tid, MNW);
  }
  const int nk = s_kept;
  if (tid < MAXDET) {
    float v0 = 0.f, v1 = 0.f, v2 = 0.f, v3 = 0.f, v4 = 0.f;
    if (tid < nk) {
      u64 key = keptkey[tid];
      int orig = NBOX - 1 - (int)(key & 0xFFFFFFFFull);
      float4 bb = bx[orig];
      v0 = bb.x; v1 = bb.y; v2 = bb.z; v3 = bb.w;
      v4 = __uint_as_float((u32)(key >> 32));
    }
    float* o = out + ((size_t)b * MAXDET + tid) * 5;
    o[0] = v0; o[1] = v1; o[2] = v2; o[3] = v3; o[4] = v4;
  }
  if (tid == 0) out[(size_t)B * MAXDET * 5 + b] = (float)nk;
}

extern "C" void kernel_launch(void* const* d_in, const int* in_sizes, int n_in,
                              void* d_out, int out_size, void* d_ws, size_t ws_size,
                              hipStream_t stream) {
  const float* boxes = (const float*)d_in[0];
  const float* scores = (const float*)d_in[1];
  float* out = (float*)d_out;
  (void)in_sizes; (void)n_in;
  const int B = out_size / (MAXDET * 5 + 1);  // [B,100,5] + [B]
  const size_t need = 256 + (size_t)B * SL * KSEL * sizeof(u64);
  if (d_ws && ws_size >= need) {
    hipMemsetAsync(d_ws, 0, 256, stream);  // reset barrier counter (graph-legal)
    u32* ctr = (u32*)d_ws;
    u64* lists = (u64*)((char*)d_ws + 256);
    pp_fused<<<B * SL, TPB, 0, stream>>>(boxes, scores, out, ctr, lists, B);
  } else {
    postproc_mono<<<B, MNT, 0, stream>>>(boxes, scores, out, B);
  }
}

// Round 8
// 32.034 us; speedup vs baseline: 1.4149x; 1.4149x over previous
//
#include <hip/hip_runtime.h>

#define NT 512
#define NBOX 4096
#define MAXDET 100
#define KSEL 192     // top-K selection target (>= 100 + NMS-suppressed margin)
#define CAP 512      // candidate capacity
#define MSMALL 320   // take-all threshold (skip histogram)

typedef unsigned long long u64;
typedef unsigned int u32;

__device__ __forceinline__ float iou_xyxy(float4 a, float4 c) {
  float aa = fmaxf(a.z - a.x, 0.f) * fmaxf(a.w - a.y, 0.f);
  float ca = fmaxf(c.z - c.x, 0.f) * fmaxf(c.w - c.y, 0.f);
  float w = fmaxf(fminf(a.z, c.z) - fmaxf(a.x, c.x), 0.f);
  float h = fmaxf(fminf(a.w, c.w) - fmaxf(a.y, c.y), 0.f);
  float inter = w * h;
  return inter / fmaxf(aa + ca - inter, 1e-9f);
}

template <int R>
__device__ __forceinline__ void merge_step(u64 (&v)[R], int lane, int k, int j) {
  if (j >= 64) {
    int jj = j >> 6;
#pragma unroll
    for (int r = 0; r < R; ++r)
      if (!(r & jj)) {
        int r2 = r | jj;
        bool up = ((r & (k >> 6)) != 0);
        u64 a = v[r], c = v[r2];
        if (up ? (a > c) : (a < c)) { v[r] = c; v[r2] = a; }
      }
  } else {
#pragma unroll
    for (int r = 0; r < R; ++r) {
      u64 a = v[r];
      u64 o = __shfl_xor(a, j);
      bool up = (k >= 64) ? ((r & (k >> 6)) != 0) : ((lane & k) != 0);
      bool keep_max = up ^ ((lane & j) == 0);
      v[r] = keep_max ? (a > o ? a : o) : (a < o ? a : o);
    }
  }
}

// Descending bitonic sort of R*64 keys from LDS, in one wave's registers.
template <int R>
__device__ __forceinline__ void wave_sort(u64* keys, int C, int lane) {
  u64 v[R];
#pragma unroll
  for (int r = 0; r < R; ++r) {
    int i = r * 64 + lane;
    v[r] = (i < C) ? keys[i] : 0ull;
  }
  const int S = R * 64;
  for (int k = 2; k <= S; k <<= 1)
    for (int j = k >> 1; j > 0; j >>= 1) merge_step<R>(v, lane, k, j);
#pragma unroll
  for (int r = 0; r < R; ++r) keys[r * 64 + lane] = v[r];
}

__device__ __forceinline__ u64 wave_or64(u64 v) {
#pragma unroll
  for (int d = 1; d < 64; d <<= 1) v |= __shfl_xor(v, d);
  return v;
}

// Exact greedy over 64 slots: rows_mine = suppression row of element `lane`.
__device__ __forceinline__ u64 serial_greedy(u64 rows_mine, u64 removed) {
  u64 keep = 0ull;
  for (int ii = 0; ii < 64; ++ii) {
    u64 row = __shfl(rows_mine, ii);
    if (!((removed >> ii) & 1ull)) { keep |= 1ull << ii; removed |= row; }
  }
  return keep;
}

// 128-wide chunked greedy NMS over sorted (descending) keys in LDS.
__device__ void run_nms128(const u64* keys, int len, const float4* __restrict__ bx,
                           float4* chbox, u64* srowLo, u64* srowHi, u64* crossM,
                           u64* keptkey, float4* keptbox, int* p_kept, int tid) {
  const int lane = tid & 63;
  for (int base = 0; base < len; base += 128) {
    if (*p_kept >= MAXDET) break;  // uniform (written before a barrier)
    const int L = min(128, len - base);
    if (tid < 128) {  // ---- stage 128 boxes (xyxy) in one parallel round ----
      if (tid < 2) crossM[tid] = 0ull;
      float4 bb = make_float4(0.f, 0.f, 0.f, 0.f);
      if (tid < L) {
        u64 k = keys[base + tid];
        int orig = NBOX - 1 - (int)(k & 0xFFFFFFFFull);
        float4 c = bx[orig];
        bb = make_float4(c.x - 0.5f * c.z, c.y - 0.5f * c.w,
                         c.x + 0.5f * c.z, c.y + 0.5f * c.w);
      }
      chbox[tid] = bb;
      srowLo[tid] = 0ull;
      srowHi[tid] = 0ull;
    }
    __syncthreads();
    const int kept0 = *p_kept;
    {  // ---- pair tests: 128 rows x 4 slices ----
      int i = tid & 127, slice = tid >> 7;
      if (i < L) {
        float4 a = chbox[i];
        bool hit = false;
        for (int k0 = slice; k0 < kept0 && !hit; k0 += 4)
          if (iou_xyxy(a, keptbox[k0]) > 0.7f) hit = true;
        if (hit) atomicOr(&crossM[i >> 6], 1ull << (i & 63));
        u64 blo = 0ull, bhi = 0ull;
        for (int j = i + 1 + slice; j < L; j += 4)
          if (iou_xyxy(a, chbox[j]) > 0.7f) {
            if (j < 64) blo |= 1ull << j; else bhi |= 1ull << (j - 64);
          }
        if (blo) atomicOr(&srowLo[i], blo);
        if (bhi) atomicOr(&srowHi[i], bhi);
      }
    }
    __syncthreads();
    if (tid < 64) {  // ---- two-half greedy resolution, wave 0 ----
      u64 remL = crossM[0], remH = crossM[1];
      if (L < 64) remL |= ~((1ull << L) - 1ull);
      if (L <= 64) remH = ~0ull;
      else if (L < 128) remH |= ~((1ull << (L - 64)) - 1ull);
      u64 rAlo = srowLo[lane], rAhi = srowHi[lane];  // row of element lane
      u64 rBhi = srowHi[64 + lane];                  // row of element 64+lane
      // half 1
      u64 K1 = ~remL;
      u64 c1 = wave_or64(((K1 >> lane) & 1ull) ? (rAlo & K1) : 0ull);
      u64 keep1 = (c1 == 0ull) ? K1 : serial_greedy(rAlo, remL);
      // cross-suppression from half-1 keepers into half 2
      u64 remH2 = remH | wave_or64(((keep1 >> lane) & 1ull) ? rAhi : 0ull);
      // half 2
      u64 K2 = ~remH2;
      u64 c2 = wave_or64(((K2 >> lane) & 1ull) ? (rBhi & K2) : 0ull);
      u64 keep2 = (c2 == 0ull) ? K2 : serial_greedy(rBhi, remH2);
      // append
      int cnt1 = (int)__popcll(keep1);
      u64 below = (1ull << lane) - 1ull;
      if ((keep1 >> lane) & 1ull) {
        int pos = kept0 + (int)__popcll(keep1 & below);
        if (pos < MAXDET) { keptkey[pos] = keys[base + lane]; keptbox[pos] = chbox[lane]; }
      }
      if ((keep2 >> lane) & 1ull) {
        int pos = kept0 + cnt1 + (int)__popcll(keep2 & below);
        if (pos < MAXDET) { keptkey[pos] = keys[base + 64 + lane]; keptbox[pos] = chbox[64 + lane]; }
      }
      if (lane == 0)
        *p_kept = min(MAXDET, kept0 + cnt1 + (int)__popcll(keep2));
    }
    __syncthreads();
  }
}

__global__ __launch_bounds__(NT) void postproc_kernel(
    const float* __restrict__ boxes,   // [B, NBOX, 4] cxcywh
    const float* __restrict__ scores,  // [B, NBOX]
    float* __restrict__ out,           // [B*MAXDET*5] packed, then [B] num
    int B) {
  const int b = blockIdx.x;
  const int tid = threadIdx.x, wid = tid >> 6, lane = tid & 63;

  __shared__ u32 hist[8][256];    // 8KB per-wave sub-histograms
  __shared__ u32 hm[256];
  __shared__ u64 cand[CAP];       // 4KB
  __shared__ u64 skey[NBOX];      // 32KB, fallback full sort only
  __shared__ float4 chbox[128];
  __shared__ u64 srowLo[128], srowHi[128];
  __shared__ u64 crossM[2];
  __shared__ float4 keptbox[MAXDET];
  __shared__ u64 keptkey[MAXDET];
  __shared__ int s_M, s_C, s_kept, s_ovf, s_byte, s_above, s_bcnt;
  __shared__ int s_minP, s_maxP;

  const float* sc = scores + (size_t)b * NBOX;
  const float4* bx = (const float4*)boxes + (size_t)b * NBOX;

  if (tid == 0) {
    s_M = 0; s_C = 0; s_kept = 0; s_ovf = 0;
    s_minP = 0x7FFFFFFF; s_maxP = -1;
  }
  __syncthreads();

  // ---- Phase 1: contiguous vector loads, keys in regs, M + prefix range ----
  u64 key[8];
  {
    const int t8 = tid * 8;
    float4 f0 = *(const float4*)(sc + t8);
    float4 f1 = *(const float4*)(sc + t8 + 4);
    float xs[8] = {f0.x, f0.y, f0.z, f0.w, f1.x, f1.y, f1.z, f1.w};
    int myM = 0, pmin = 0x7FFFFFFF, pmax = -1;
#pragma unroll
    for (int q = 0; q < 8; ++q) {
      float x = xs[q];
      bool valid = (x > 0.5f);
      u32 bits = __float_as_uint(x);
      key[q] = valid ? (((u64)bits << 32) | (u64)(u32)(NBOX - 1 - (t8 + q))) : 0ull;
      if (valid) {
        int p = (int)(bits >> 23);
        pmin = min(pmin, p); pmax = max(pmax, p); ++myM;
      }
    }
#pragma unroll
    for (int d = 1; d < 64; d <<= 1) {
      myM += __shfl_xor(myM, d);
      pmin = min(pmin, __shfl_xor(pmin, d));
      pmax = max(pmax, __shfl_xor(pmax, d));
    }
    if (lane == 0) {
      atomicAdd(&s_M, myM);
      atomicMin(&s_minP, pmin);
      atomicMax(&s_maxP, pmax);
    }
  }
  __syncthreads();
  const int M = s_M;
  const bool uniformP = (s_minP == s_maxP);  // all valid share exponent+sign bits
  bool fullpath = false;
  bool usehist = false;
  u32 thr = 0;

  // ---- Phase 2: selection threshold (1-pass mantissa histogram) ----
  if (M > MSMALL) {
    if (uniformP) {
      usehist = true;
      for (int h = tid; h < 8 * 256; h += NT) ((u32*)hist)[h] = 0u;
      __syncthreads();
#pragma unroll
      for (int q = 0; q < 8; ++q)
        if (key[q]) atomicAdd(&hist[wid][(u32)(key[q] >> 47) & 255u], 1u);
      __syncthreads();
      if (tid < 256) {
        u32 t = 0;
#pragma unroll
        for (int w = 0; w < 8; ++w) t += hist[w][tid];
        hm[tid] = t;
      }
      __syncthreads();
      if (tid < 64) {  // suffix scan over 256 bins, 4/lane (bins ascend in value)
        int c0 = hm[tid * 4], c1 = hm[tid * 4 + 1], c2 = hm[tid * 4 + 2], c3 = hm[tid * 4 + 3];
        int tot = c0 + c1 + c2 + c3;
        int suf = tot;
#pragma unroll
        for (int d = 1; d < 64; d <<= 1) {
          int o = __shfl_down(suf, d);
          if (tid + d < 64) suf += o;
        }
        if (suf - tot < KSEL && suf >= KSEL) {  // unique crossing lane
          int cc[4] = {c0, c1, c2, c3};
          int cum = suf - tot;
          for (int qq = 3; qq >= 0; --qq) {
            if (cum + cc[qq] >= KSEL) { s_byte = tid * 4 + qq; s_above = cum; s_bcnt = cc[qq]; break; }
            cum += cc[qq];
          }
        }
      }
      __syncthreads();
      thr = (u32)s_byte;
      if (s_above + s_bcnt > CAP) fullpath = true;
    } else {
      fullpath = true;
    }
  }

  // ---- Phase 3: compact candidates (wave-aggregated atomics) ----
  if (!fullpath) {
#pragma unroll
    for (int q = 0; q < 8; ++q) {
      bool take = key[q] && (!usehist || (((u32)(key[q] >> 47) & 255u) >= thr));
      u64 bal = __ballot(take);
      if (bal) {
        int leader = __ffsll((unsigned long long)bal) - 1;
        int basep = 0;
        if (lane == leader) basep = atomicAdd(&s_C, (int)__popcll(bal));
        basep = __shfl(basep, leader);
        if (take) {
          int pos = basep + (int)__popcll(bal & ((1ull << lane) - 1ull));
          if (pos < CAP) cand[pos] = key[q];
          else s_ovf = 1;
        }
      }
    }
  }
  __syncthreads();
  const int C = min(s_C, CAP);
  if (s_ovf) fullpath = true;

  // ---- Phase 4: single-wave register sort + 128-chunk NMS ----
  if (!fullpath && C > 0) {
    if (wid == 0) {
      if (C <= 256) wave_sort<4>(cand, C, lane);
      else wave_sort<8>(cand, C, lane);
    }
    __syncthreads();
    run_nms128(cand, C, bx, chbox, srowLo, srowHi, crossM, keptkey, keptbox, &s_kept, tid);
  }

  // ---- Phase 5: fully-general fallback (pathological inputs only) ----
  const int kept1 = s_kept;
  const bool selDropped = usehist && (C < M);
  const bool need_full = fullpath || (kept1 < MAXDET && selDropped);
  __syncthreads();
  if (need_full) {
    if (tid == 0) s_kept = 0;
#pragma unroll
    for (int q = 0; q < 8; ++q) {
      int n = tid * 8 + q;
      skey[n] = key[q] ? key[q] : (u64)(u32)(NBOX - 1 - n);
    }
    __syncthreads();
    for (int k = 2; k <= NBOX; k <<= 1)
      for (int j = k >> 1; j > 0; j >>= 1) {
        for (int t = tid; t < NBOX; t += NT) {
          int ixj = t ^ j;
          if (ixj > t) {
            u64 a = skey[t], c2 = skey[ixj];
            bool up = (t & k) != 0;
            if (up ? (a > c2) : (a < c2)) { skey[t] = c2; skey[ixj] = a; }
          }
        }
        __syncthreads();
      }
    run_nms128(skey, M, bx, chbox, srowLo, srowHi, crossM, keptkey, keptbox, &s_kept, tid);
  }

  // ---- Phase 6: outputs ----
  const int nk = s_kept;
  if (tid < MAXDET) {
    float v0 = 0.f, v1 = 0.f, v2 = 0.f, v3 = 0.f, v4 = 0.f;
    if (tid < nk) {
      u64 k = keptkey[tid];
      int orig = NBOX - 1 - (int)(k & 0xFFFFFFFFull);
      float4 bb = bx[orig];  // original cxcywh
      v0 = bb.x; v1 = bb.y; v2 = bb.z; v3 = bb.w;
      v4 = __uint_as_float((u32)(k >> 32));
    }
    float* o = out + ((size_t)b * MAXDET + tid) * 5;
    o[0] = v0; o[1] = v1; o[2] = v2; o[3] = v3; o[4] = v4;
  }
  if (tid == 0) out[(size_t)B * MAXDET * 5 + b] = (float)nk;
}

extern "C" void kernel_launch(void* const* d_in, const int* in_sizes, int n_in,
                              void* d_out, int out_size, void* d_ws, size_t ws_size,
                              hipStream_t stream) {
  const float* boxes = (const float*)d_in[0];
  const float* scores = (const float*)d_in[1];
  float* out = (float*)d_out;
  (void)d_ws; (void)ws_size; (void)n_in;
  const int B = out_size / (MAXDET * 5 + 1);  // [B,100,5] + [B]
  postproc_kernel<<<B, NT, 0, stream>>>(boxes, scores, out, B);
}

// Round 9
// 30.524 us; speedup vs baseline: 1.4849x; 1.0495x over previous
//
#include <hip/hip_runtime.h>

#define NT 1024
#define NW 16        // waves per block
#define NBOX 4096
#define NPT 4        // scores per thread
#define MAXDET 100
#define KSEL 192     // top-K selection target (>= 100 + NMS-suppressed margin)
#define CAP 512      // candidate capacity
#define MSMALL 320   // take-all threshold (skip histogram)

typedef unsigned long long u64;
typedef unsigned int u32;

__device__ __forceinline__ float iou_xyxy(float4 a, float4 c) {
  float aa = fmaxf(a.z - a.x, 0.f) * fmaxf(a.w - a.y, 0.f);
  float ca = fmaxf(c.z - c.x, 0.f) * fmaxf(c.w - c.y, 0.f);
  float w = fmaxf(fminf(a.z, c.z) - fmaxf(a.x, c.x), 0.f);
  float h = fmaxf(fminf(a.w, c.w) - fmaxf(a.y, c.y), 0.f);
  float inter = w * h;
  return inter / fmaxf(aa + ca - inter, 1e-9f);
}

template <int R>
__device__ __forceinline__ void merge_step(u64 (&v)[R], int lane, int k, int j) {
  if (j >= 64) {
    int jj = j >> 6;
#pragma unroll
    for (int r = 0; r < R; ++r)
      if (!(r & jj)) {
        int r2 = r | jj;
        bool up = ((r & (k >> 6)) != 0);
        u64 a = v[r], c = v[r2];
        if (up ? (a > c) : (a < c)) { v[r] = c; v[r2] = a; }
      }
  } else {
#pragma unroll
    for (int r = 0; r < R; ++r) {
      u64 a = v[r];
      u64 o = __shfl_xor(a, j);
      bool up = (k >= 64) ? ((r & (k >> 6)) != 0) : ((lane & k) != 0);
      bool keep_max = up ^ ((lane & j) == 0);
      v[r] = keep_max ? (a > o ? a : o) : (a < o ? a : o);
    }
  }
}

// Descending bitonic sort of R*64 keys from LDS, in one wave's registers.
template <int R>
__device__ __forceinline__ void wave_sort(u64* keys, int C, int lane) {
  u64 v[R];
#pragma unroll
  for (int r = 0; r < R; ++r) {
    int i = r * 64 + lane;
    v[r] = (i < C) ? keys[i] : 0ull;
  }
  const int S = R * 64;
  for (int k = 2; k <= S; k <<= 1)
    for (int j = k >> 1; j > 0; j >>= 1) merge_step<R>(v, lane, k, j);
#pragma unroll
  for (int r = 0; r < R; ++r) keys[r * 64 + lane] = v[r];
}

__device__ __forceinline__ u64 wave_or64(u64 v) {
#pragma unroll
  for (int d = 1; d < 64; d <<= 1) v |= __shfl_xor(v, d);
  return v;
}

// Exact greedy over 64 slots: rows_mine = suppression row of element `lane`.
__device__ __forceinline__ u64 serial_greedy(u64 rows_mine, u64 removed) {
  u64 keep = 0ull;
  for (int ii = 0; ii < 64; ++ii) {
    u64 row = __shfl(rows_mine, ii);
    if (!((removed >> ii) & 1ull)) { keep |= 1ull << ii; removed |= row; }
  }
  return keep;
}

// 128-wide chunked greedy NMS over sorted (descending) keys in LDS.
// keptxy = kept xyxy (for cross tests); keptcw = kept cxcywh (for output).
__device__ void run_nms128(const u64* keys, int len, const float4* __restrict__ bx,
                           float4* chbox, float4* chcw, u64* srowLo, u64* srowHi,
                           u64* crossM, u64* keptkey, float4* keptxy, float4* keptcw,
                           int* p_kept, int tid) {
  const int lane = tid & 63;
  for (int base = 0; base < len; base += 128) {
    if (*p_kept >= MAXDET) break;  // uniform (written before a barrier)
    const int L = min(128, len - base);
    if (tid < 128) {  // ---- stage 128 boxes in one parallel round ----
      if (tid < 2) crossM[tid] = 0ull;
      float4 bb = make_float4(0.f, 0.f, 0.f, 0.f);
      float4 c = make_float4(0.f, 0.f, 0.f, 0.f);
      if (tid < L) {
        u64 k = keys[base + tid];
        int orig = NBOX - 1 - (int)(k & 0xFFFFFFFFull);
        c = bx[orig];
        bb = make_float4(c.x - 0.5f * c.z, c.y - 0.5f * c.w,
                         c.x + 0.5f * c.z, c.y + 0.5f * c.w);
      }
      chbox[tid] = bb;
      chcw[tid] = c;
      srowLo[tid] = 0ull;
      srowHi[tid] = 0ull;
    }
    __syncthreads();
    const int kept0 = *p_kept;
    {  // ---- pair tests: 128 rows x 8 slices ----
      int i = tid & 127, slice = tid >> 7;
      if (i < L) {
        float4 a = chbox[i];
        bool hit = false;
        for (int k0 = slice; k0 < kept0 && !hit; k0 += 8)
          if (iou_xyxy(a, keptxy[k0]) > 0.7f) hit = true;
        if (hit) atomicOr(&crossM[i >> 6], 1ull << (i & 63));
        u64 blo = 0ull, bhi = 0ull;
        for (int j = i + 1 + slice; j < L; j += 8)
          if (iou_xyxy(a, chbox[j]) > 0.7f) {
            if (j < 64) blo |= 1ull << j; else bhi |= 1ull << (j - 64);
          }
        if (blo) atomicOr(&srowLo[i], blo);
        if (bhi) atomicOr(&srowHi[i], bhi);
      }
    }
    __syncthreads();
    if (tid < 64) {  // ---- two-half greedy resolution, wave 0 ----
      u64 remL = crossM[0], remH = crossM[1];
      if (L < 64) remL |= ~((1ull << L) - 1ull);
      if (L <= 64) remH = ~0ull;
      else if (L < 128) remH |= ~((1ull << (L - 64)) - 1ull);
      u64 rAlo = srowLo[lane], rAhi = srowHi[lane];  // row of element lane
      u64 rBhi = srowHi[64 + lane];                  // row of element 64+lane
      // half 1
      u64 K1 = ~remL;
      u64 c1 = wave_or64(((K1 >> lane) & 1ull) ? (rAlo & K1) : 0ull);
      u64 keep1 = (c1 == 0ull) ? K1 : serial_greedy(rAlo, remL);
      // cross-suppression from half-1 keepers into half 2
      u64 remH2 = remH | wave_or64(((keep1 >> lane) & 1ull) ? rAhi : 0ull);
      // half 2
      u64 K2 = ~remH2;
      u64 c2 = wave_or64(((K2 >> lane) & 1ull) ? (rBhi & K2) : 0ull);
      u64 keep2 = (c2 == 0ull) ? K2 : serial_greedy(rBhi, remH2);
      // append
      int cnt1 = (int)__popcll(keep1);
      u64 below = (1ull << lane) - 1ull;
      if ((keep1 >> lane) & 1ull) {
        int pos = kept0 + (int)__popcll(keep1 & below);
        if (pos < MAXDET) {
          keptkey[pos] = keys[base + lane];
          keptxy[pos] = chbox[lane];
          keptcw[pos] = chcw[lane];
        }
      }
      if ((keep2 >> lane) & 1ull) {
        int pos = kept0 + cnt1 + (int)__popcll(keep2 & below);
        if (pos < MAXDET) {
          keptkey[pos] = keys[base + 64 + lane];
          keptxy[pos] = chbox[64 + lane];
          keptcw[pos] = chcw[64 + lane];
        }
      }
      if (lane == 0)
        *p_kept = min(MAXDET, kept0 + cnt1 + (int)__popcll(keep2));
    }
    __syncthreads();
  }
}

__global__ __launch_bounds__(NT) void postproc_kernel(
    const float* __restrict__ boxes,   // [B, NBOX, 4] cxcywh
    const float* __restrict__ scores,  // [B, NBOX]
    float* __restrict__ out,           // [B*MAXDET*5] packed, then [B] num
    int B) {
  const int b = blockIdx.x;
  const int tid = threadIdx.x, wid = tid >> 6, lane = tid & 63;

  __shared__ u32 hist[NW][256];   // 16KB per-wave sub-histograms
  __shared__ u32 hm[256];
  __shared__ u64 cand[CAP];       // 4KB
  __shared__ u64 skey[NBOX];      // 32KB, fallback full sort only
  __shared__ float4 chbox[128];   // chunk xyxy
  __shared__ float4 chcw[128];    // chunk cxcywh
  __shared__ u64 srowLo[128], srowHi[128];
  __shared__ u64 crossM[2];
  __shared__ float4 keptxy[MAXDET];
  __shared__ float4 keptcw[MAXDET];
  __shared__ u64 keptkey[MAXDET];
  __shared__ int s_M, s_C, s_kept, s_ovf, s_byte, s_above, s_bcnt;
  __shared__ int s_minP, s_maxP;

  const float* sc = scores + (size_t)b * NBOX;
  const float4* bx = (const float4*)boxes + (size_t)b * NBOX;

  if (tid == 0) {
    s_M = 0; s_C = 0; s_kept = 0; s_ovf = 0;
    s_minP = 0x7FFFFFFF; s_maxP = -1;
  }

  // ---- Phase 1: one float4 of scores per thread; keys in regs; M + exp range ----
  u64 key[NPT];
  {
    const int t4 = tid * NPT;
    float4 f0 = *(const float4*)(sc + t4);
    float xs[NPT] = {f0.x, f0.y, f0.z, f0.w};
    int myM = 0, pmin = 0x7FFFFFFF, pmax = -1;
#pragma unroll
    for (int q = 0; q < NPT; ++q) {
      float x = xs[q];
      bool valid = (x > 0.5f);
      u32 bits = __float_as_uint(x);
      key[q] = valid ? (((u64)bits << 32) | (u64)(u32)(NBOX - 1 - (t4 + q))) : 0ull;
      if (valid) {
        int p = (int)(bits >> 23);
        pmin = min(pmin, p); pmax = max(pmax, p); ++myM;
      }
    }
#pragma unroll
    for (int d = 1; d < 64; d <<= 1) {
      myM += __shfl_xor(myM, d);
      pmin = min(pmin, __shfl_xor(pmin, d));
      pmax = max(pmax, __shfl_xor(pmax, d));
    }
    __syncthreads();  // s_* init visible
    if (lane == 0) {
      atomicAdd(&s_M, myM);
      atomicMin(&s_minP, pmin);
      atomicMax(&s_maxP, pmax);
    }
  }
  __syncthreads();
  const int M = s_M;
  const bool uniformP = (s_minP == s_maxP);  // all valid share sign+exponent
  bool fullpath = false;
  bool usehist = false;
  u32 thr = 0;

  // ---- Phase 2: selection threshold (1-pass mantissa histogram) ----
  if (M > MSMALL) {
    if (uniformP) {
      usehist = true;
      for (int h = tid; h < NW * 256; h += NT) ((u32*)hist)[h] = 0u;
      __syncthreads();
#pragma unroll
      for (int q = 0; q < NPT; ++q)
        if (key[q]) atomicAdd(&hist[wid][(u32)(key[q] >> 47) & 255u], 1u);
      __syncthreads();
      if (tid < 256) {
        u32 t = 0;
#pragma unroll
        for (int w = 0; w < NW; ++w) t += hist[w][tid];
        hm[tid] = t;
      }
      __syncthreads();
      if (tid < 64) {  // suffix scan over 256 bins, 4/lane (bins ascend)
        int c0 = hm[tid * 4], c1 = hm[tid * 4 + 1], c2 = hm[tid * 4 + 2], c3 = hm[tid * 4 + 3];
        int tot = c0 + c1 + c2 + c3;
        int suf = tot;
#pragma unroll
        for (int d = 1; d < 64; d <<= 1) {
          int o = __shfl_down(suf, d);
          if (tid + d < 64) suf += o;
        }
        if (suf - tot < KSEL && suf >= KSEL) {  // unique crossing lane
          int cc[4] = {c0, c1, c2, c3};
          int cum = suf - tot;
          for (int qq = 3; qq >= 0; --qq) {
            if (cum + cc[qq] >= KSEL) { s_byte = tid * 4 + qq; s_above = cum; s_bcnt = cc[qq]; break; }
            cum += cc[qq];
          }
        }
      }
      __syncthreads();
      thr = (u32)s_byte;
      if (s_above + s_bcnt > CAP) fullpath = true;
    } else {
      fullpath = true;
    }
  }

  // ---- Phase 3: compact candidates (wave-aggregated atomics) ----
  if (!fullpath) {
#pragma unroll
    for (int q = 0; q < NPT; ++q) {
      bool take = key[q] && (!usehist || (((u32)(key[q] >> 47) & 255u) >= thr));
      u64 bal = __ballot(take);
      if (bal) {
        int leader = __ffsll((unsigned long long)bal) - 1;
        int basep = 0;
        if (lane == leader) basep = atomicAdd(&s_C, (int)__popcll(bal));
        basep = __shfl(basep, leader);
        if (take) {
          int pos = basep + (int)__popcll(bal & ((1ull << lane) - 1ull));
          if (pos < CAP) cand[pos] = key[q];
          else s_ovf = 1;
        }
      }
    }
  }
  __syncthreads();
  const int C = min(s_C, CAP);
  if (s_ovf) fullpath = true;

  // ---- Phase 4: single-wave register sort + 128-chunk NMS ----
  if (!fullpath && C > 0) {
    if (wid == 0) {
      if (C <= 256) wave_sort<4>(cand, C, lane);
      else wave_sort<8>(cand, C, lane);
    }
    __syncthreads();
    run_nms128(cand, C, bx, chbox, chcw, srowLo, srowHi, crossM,
               keptkey, keptxy, keptcw, &s_kept, tid);
  }

  // ---- Phase 5: fully-general fallback (pathological inputs only) ----
  const int kept1 = s_kept;
  const bool selDropped = usehist && (C < M);
  const bool need_full = fullpath || (kept1 < MAXDET && selDropped);
  __syncthreads();
  if (need_full) {
    if (tid == 0) s_kept = 0;
#pragma unroll
    for (int q = 0; q < NPT; ++q) {
      int n = tid * NPT + q;
      skey[n] = key[q] ? key[q] : (u64)(u32)(NBOX - 1 - n);
    }
    __syncthreads();
    for (int k = 2; k <= NBOX; k <<= 1)
      for (int j = k >> 1; j > 0; j >>= 1) {
#pragma clang loop unroll(disable)
        for (int t = tid; t < NBOX; t += NT) {
          int ixj = t ^ j;
          if (ixj > t) {
            u64 a = skey[t], c2 = skey[ixj];
            bool up = (t & k) != 0;
            if (up ? (a > c2) : (a < c2)) { skey[t] = c2; skey[ixj] = a; }
          }
        }
        __syncthreads();
      }
    run_nms128(skey, M, bx, chbox, chcw, srowLo, srowHi, crossM,
               keptkey, keptxy, keptcw, &s_kept, tid);
  }

  // ---- Phase 6: outputs (all from LDS; coalesced stores) ----
  const int nk = s_kept;
  if (tid < MAXDET) {
    float v0 = 0.f, v1 = 0.f, v2 = 0.f, v3 = 0.f, v4 = 0.f;
    if (tid < nk) {
      float4 bb = keptcw[tid];  // original cxcywh (staged during NMS)
      v0 = bb.x; v1 = bb.y; v2 = bb.z; v3 = bb.w;
      v4 = __uint_as_float((u32)(keptkey[tid] >> 32));
    }
    float* o = out + ((size_t)b * MAXDET + tid) * 5;
    o[0] = v0; o[1] = v1; o[2] = v2; o[3] = v3; o[4] = v4;
  }
  if (tid == 0) out[(size_t)B * MAXDET * 5 + b] = (float)nk;
}

extern "C" void kernel_launch(void* const* d_in, const int* in_sizes, int n_in,
                              void* d_out, int out_size, void* d_ws, size_t ws_size,
                              hipStream_t stream) {
  const float* boxes = (const float*)d_in[0];
  const float* scores = (const float*)d_in[1];
  float* out = (float*)d_out;
  (void)d_ws; (void)ws_size; (void)n_in;
  const int B = out_size / (MAXDET * 5 + 1);  // [B,100,5] + [B]
  postproc_kernel<<<B, NT, 0, stream>>>(boxes, scores, out, B);
}

// Round 10
// 25.433 us; speedup vs baseline: 1.7821x; 1.2002x over previous
//
#include <hip/hip_runtime.h>

#define NT 1024
#define NW 16        // waves per block
#define NH 4         // sub-histograms
#define NBOX 4096
#define NPT 4        // scores per thread
#define MAXDET 100
#define KSEL 192     // top-K selection target (>= 100 + NMS-suppressed margin)
#define CAP 512      // candidate capacity
#define MSMALL 320   // take-all threshold (skip histogram)

typedef unsigned long long u64;
typedef unsigned int u32;
typedef unsigned short u16;

__device__ __forceinline__ float iou_xyxy(float4 a, float4 c) {
  float aa = fmaxf(a.z - a.x, 0.f) * fmaxf(a.w - a.y, 0.f);
  float ca = fmaxf(c.z - c.x, 0.f) * fmaxf(c.w - c.y, 0.f);
  float w = fmaxf(fminf(a.z, c.z) - fmaxf(a.x, c.x), 0.f);
  float h = fmaxf(fminf(a.w, c.w) - fmaxf(a.y, c.y), 0.f);
  float inter = w * h;
  return inter / fmaxf(aa + ca - inter, 1e-9f);
}

__device__ __forceinline__ u64 wave_or64(u64 v) {
#pragma unroll
  for (int d = 1; d < 64; d <<= 1) v |= __shfl_xor(v, d);
  return v;
}

// Exact greedy over 64 slots: rows_mine = suppression row of element `lane`.
__device__ __forceinline__ u64 serial_greedy(u64 rows_mine, u64 removed) {
  u64 keep = 0ull;
  for (int ii = 0; ii < 64; ++ii) {
    u64 row = __shfl(rows_mine, ii);
    if (!((removed >> ii) & 1ull)) { keep |= 1ull << ii; removed |= row; }
  }
  return keep;
}

// 128-wide chunked greedy NMS over sorted (descending) keys.
// LDSBOX: boxes come from cbst[sortedSlot[.]] in LDS; else scattered global bx.
template <bool LDSBOX>
__device__ void run_nms128(const u64* keys, int len, const float4* __restrict__ bx,
                           const u16* sortedSlot, const float4* cbst,
                           float4* chbox, float4* chcw, u64* srowLo, u64* srowHi,
                           u64* crossM, u64* keptkey, float4* keptxy, float4* keptcw,
                           int* p_kept, int tid) {
  const int lane = tid & 63;
  for (int base = 0; base < len; base += 128) {
    if (*p_kept >= MAXDET) break;  // uniform (written before a barrier)
    const int L = min(128, len - base);
    if (tid < 128) {  // ---- stage 128 boxes in one parallel round ----
      if (tid < 2) crossM[tid] = 0ull;
      float4 bb = make_float4(0.f, 0.f, 0.f, 0.f);
      float4 c = make_float4(0.f, 0.f, 0.f, 0.f);
      if (tid < L) {
        if (LDSBOX) {
          c = cbst[sortedSlot[base + tid]];
        } else {
          u64 k = keys[base + tid];
          int orig = NBOX - 1 - (int)(k & 0xFFFFFFFFull);
          c = bx[orig];
        }
        bb = make_float4(c.x - 0.5f * c.z, c.y - 0.5f * c.w,
                         c.x + 0.5f * c.z, c.y + 0.5f * c.w);
      }
      chbox[tid] = bb;
      chcw[tid] = c;
      srowLo[tid] = 0ull;
      srowHi[tid] = 0ull;
    }
    __syncthreads();
    const int kept0 = *p_kept;
    {  // ---- pair tests: 128 rows x 8 slices ----
      int i = tid & 127, slice = tid >> 7;
      if (i < L) {
        float4 a = chbox[i];
        bool hit = false;
        for (int k0 = slice; k0 < kept0 && !hit; k0 += 8)
          if (iou_xyxy(a, keptxy[k0]) > 0.7f) hit = true;
        if (hit) atomicOr(&crossM[i >> 6], 1ull << (i & 63));
        u64 blo = 0ull, bhi = 0ull;
        for (int j = i + 1 + slice; j < L; j += 8)
          if (iou_xyxy(a, chbox[j]) > 0.7f) {
            if (j < 64) blo |= 1ull << j; else bhi |= 1ull << (j - 64);
          }
        if (blo) atomicOr(&srowLo[i], blo);
        if (bhi) atomicOr(&srowHi[i], bhi);
      }
    }
    __syncthreads();
    if (tid < 64) {  // ---- two-half greedy resolution, wave 0 ----
      u64 remL = crossM[0], remH = crossM[1];
      if (L < 64) remL |= ~((1ull << L) - 1ull);
      if (L <= 64) remH = ~0ull;
      else if (L < 128) remH |= ~((1ull << (L - 64)) - 1ull);
      u64 rAlo = srowLo[lane], rAhi = srowHi[lane];  // row of element lane
      u64 rBhi = srowHi[64 + lane];                  // row of element 64+lane
      // half 1
      u64 K1 = ~remL;
      u64 c1 = wave_or64(((K1 >> lane) & 1ull) ? (rAlo & K1) : 0ull);
      u64 keep1 = (c1 == 0ull) ? K1 : serial_greedy(rAlo, remL);
      // cross-suppression from half-1 keepers into half 2
      u64 remH2 = remH | wave_or64(((keep1 >> lane) & 1ull) ? rAhi : 0ull);
      // half 2
      u64 K2 = ~remH2;
      u64 c2 = wave_or64(((K2 >> lane) & 1ull) ? (rBhi & K2) : 0ull);
      u64 keep2 = (c2 == 0ull) ? K2 : serial_greedy(rBhi, remH2);
      // append
      int cnt1 = (int)__popcll(keep1);
      u64 below = (1ull << lane) - 1ull;
      if ((keep1 >> lane) & 1ull) {
        int pos = kept0 + (int)__popcll(keep1 & below);
        if (pos < MAXDET) {
          keptkey[pos] = keys[base + lane];
          keptxy[pos] = chbox[lane];
          keptcw[pos] = chcw[lane];
        }
      }
      if ((keep2 >> lane) & 1ull) {
        int pos = kept0 + cnt1 + (int)__popcll(keep2 & below);
        if (pos < MAXDET) {
          keptkey[pos] = keys[base + 64 + lane];
          keptxy[pos] = chbox[64 + lane];
          keptcw[pos] = chcw[64 + lane];
        }
      }
      if (lane == 0)
        *p_kept = min(MAXDET, kept0 + cnt1 + (int)__popcll(keep2));
    }
    __syncthreads();
  }
}

__global__ __launch_bounds__(NT) void postproc_kernel(
    const float* __restrict__ boxes,   // [B, NBOX, 4] cxcywh
    const float* __restrict__ scores,  // [B, NBOX]
    float* __restrict__ out,           // [B*MAXDET*5] packed, then [B] num
    int B) {
  const int b = blockIdx.x;
  const int tid = threadIdx.x, wid = tid >> 6, lane = tid & 63;

  __shared__ u32 hist[NH][256];    // 4KB sub-histograms
  __shared__ u32 hm[256];
  __shared__ u64 cand[CAP];        // compaction order
  __shared__ u64 sortedCand[CAP];  // rank order (descending)
  __shared__ u16 sortedSlot[CAP];  // rank -> compaction slot
  __shared__ float4 cbst[CAP];     // slot -> cxcywh box (LDS-prefetched)
  __shared__ u64 skey[NBOX];       // 32KB, fallback full sort only
  __shared__ float4 chbox[128];    // chunk xyxy
  __shared__ float4 chcw[128];     // chunk cxcywh
  __shared__ u64 srowLo[128], srowHi[128];
  __shared__ u64 crossM[2];
  __shared__ float4 keptxy[MAXDET];
  __shared__ float4 keptcw[MAXDET];
  __shared__ u64 keptkey[MAXDET];
  __shared__ int s_M, s_C, s_kept, s_ovf, s_byte, s_above, s_bcnt;
  __shared__ int s_minP, s_maxP;

  const float* sc = scores + (size_t)b * NBOX;
  const float4* bx = (const float4*)boxes + (size_t)b * NBOX;

  if (tid == 0) {
    s_M = 0; s_C = 0; s_kept = 0; s_ovf = 0;
    s_minP = 0x7FFFFFFF; s_maxP = -1;
  }

  // ---- Phase 1: one float4 of scores/thread; keys in regs; M + exp range ----
  u64 key[NPT];
  {
    const int t4 = tid * NPT;
    float4 f0 = *(const float4*)(sc + t4);
    float xs[NPT] = {f0.x, f0.y, f0.z, f0.w};
    int myM = 0, pmin = 0x7FFFFFFF, pmax = -1;
#pragma unroll
    for (int q = 0; q < NPT; ++q) {
      float x = xs[q];
      bool valid = (x > 0.5f);
      u32 bits = __float_as_uint(x);
      key[q] = valid ? (((u64)bits << 32) | (u64)(u32)(NBOX - 1 - (t4 + q))) : 0ull;
      if (valid) {
        int p = (int)(bits >> 23);
        pmin = min(pmin, p); pmax = max(pmax, p); ++myM;
      }
    }
#pragma unroll
    for (int d = 1; d < 64; d <<= 1) {
      myM += __shfl_xor(myM, d);
      pmin = min(pmin, __shfl_xor(pmin, d));
      pmax = max(pmax, __shfl_xor(pmax, d));
    }
    __syncthreads();  // s_* init visible
    if (lane == 0) {
      atomicAdd(&s_M, myM);
      atomicMin(&s_minP, pmin);
      atomicMax(&s_maxP, pmax);
    }
  }
  __syncthreads();
  const int M = s_M;
  const bool uniformP = (s_minP == s_maxP);  // all valid share sign+exponent
  bool fullpath = false;
  bool usehist = false;
  u32 thr = 0;

  // ---- Phase 2: selection threshold (1-pass mantissa histogram) ----
  if (M > MSMALL) {
    if (uniformP) {
      usehist = true;
      if (tid < NH * 256) ((u32*)hist)[tid] = 0u;
      __syncthreads();
#pragma unroll
      for (int q = 0; q < NPT; ++q)
        if (key[q]) atomicAdd(&hist[wid >> 2][(u32)(key[q] >> 47) & 255u], 1u);
      __syncthreads();
      if (tid < 256) {
        u32 t = hist[0][tid] + hist[1][tid] + hist[2][tid] + hist[3][tid];
        hm[tid] = t;
      }
      __syncthreads();
      if (tid < 64) {  // suffix scan over 256 bins, 4/lane (bins ascend)
        int c0 = hm[tid * 4], c1 = hm[tid * 4 + 1], c2 = hm[tid * 4 + 2], c3 = hm[tid * 4 + 3];
        int tot = c0 + c1 + c2 + c3;
        int suf = tot;
#pragma unroll
        for (int d = 1; d < 64; d <<= 1) {
          int o = __shfl_down(suf, d);
          if (tid + d < 64) suf += o;
        }
        if (suf - tot < KSEL && suf >= KSEL) {  // unique crossing lane
          int cc[4] = {c0, c1, c2, c3};
          int cum = suf - tot;
          for (int qq = 3; qq >= 0; --qq) {
            if (cum + cc[qq] >= KSEL) { s_byte = tid * 4 + qq; s_above = cum; s_bcnt = cc[qq]; break; }
            cum += cc[qq];
          }
        }
      }
      __syncthreads();
      thr = (u32)s_byte;
      if (s_above + s_bcnt > CAP) fullpath = true;
    } else {
      fullpath = true;
    }
  }

  // ---- Phase 3: compact candidates (wave-aggregated atomics) ----
  if (!fullpath) {
#pragma unroll
    for (int q = 0; q < NPT; ++q) {
      bool take = key[q] && (!usehist || (((u32)(key[q] >> 47) & 255u) >= thr));
      u64 bal = __ballot(take);
      if (bal) {
        int leader = __ffsll((unsigned long long)bal) - 1;
        int basep = 0;
        if (lane == leader) basep = atomicAdd(&s_C, (int)__popcll(bal));
        basep = __shfl(basep, leader);
        if (take) {
          int pos = basep + (int)__popcll(bal & ((1ull << lane) - 1ull));
          if (pos < CAP) cand[pos] = key[q];
          else s_ovf = 1;
        }
      }
    }
  }
  __syncthreads();
  const int C = min(s_C, CAP);
  if (s_ovf) fullpath = true;

  // ---- Phase 4: box prefetch + parallel rank-sort + 128-chunk NMS ----
  if (!fullpath && C > 0) {
    // (a) issue scattered box gathers early (latency hides under ranking)
    float4 gbox;
    const bool hasg = (tid < C);
    if (hasg) {
      u64 k = cand[tid];
      int orig = NBOX - 1 - (int)(k & 0xFFFFFFFFull);
      gbox = bx[orig];
    }
    // (b) exact rank: 2 threads per candidate, strided halves
    {
      int i = tid >> 1, sl = tid & 1;
      if (i < C) {
        u64 ki = cand[i];
        int cnt = 0;
        for (int j = sl; j < C; j += 2) cnt += (cand[j] > ki) ? 1 : 0;
        cnt += __shfl_xor(cnt, 1);  // partner lane^1 handles same candidate
        if (sl == 0) { sortedCand[cnt] = ki; sortedSlot[cnt] = (u16)i; }
      }
    }
    // (c) land gathered boxes into LDS
    if (hasg) cbst[tid] = gbox;
    __syncthreads();
    run_nms128<true>(sortedCand, C, bx, sortedSlot, cbst, chbox, chcw,
                     srowLo, srowHi, crossM, keptkey, keptxy, keptcw, &s_kept, tid);
  }

  // ---- Phase 5: fully-general fallback (pathological inputs only) ----
  const int kept1 = s_kept;
  const bool selDropped = usehist && (C < M);
  const bool need_full = fullpath || (kept1 < MAXDET && selDropped);
  __syncthreads();
  if (need_full) {
    if (tid == 0) s_kept = 0;
#pragma unroll
    for (int q = 0; q < NPT; ++q) {
      int n = tid * NPT + q;
      skey[n] = key[q] ? key[q] : (u64)(u32)(NBOX - 1 - n);
    }
    __syncthreads();
    for (int k = 2; k <= NBOX; k <<= 1)
      for (int j = k >> 1; j > 0; j >>= 1) {
#pragma clang loop unroll(disable)
        for (int t = tid; t < NBOX; t += NT) {
          int ixj = t ^ j;
          if (ixj > t) {
            u64 a = skey[t], c2 = skey[ixj];
            bool up = (t & k) != 0;
            if (up ? (a > c2) : (a < c2)) { skey[t] = c2; skey[ixj] = a; }
          }
        }
        __syncthreads();
      }
    run_nms128<false>(skey, s_M, bx, sortedSlot, cbst, chbox, chcw,
                      srowLo, srowHi, crossM, keptkey, keptxy, keptcw, &s_kept, tid);
  }

  // ---- Phase 6: outputs (all from LDS; coalesced stores) ----
  const int nk = s_kept;
  if (tid < MAXDET) {
    float v0 = 0.f, v1 = 0.f, v2 = 0.f, v3 = 0.f, v4 = 0.f;
    if (tid < nk) {
      float4 bb = keptcw[tid];  // original cxcywh (staged during NMS)
      v0 = bb.x; v1 = bb.y; v2 = bb.z; v3 = bb.w;
      v4 = __uint_as_float((u32)(keptkey[tid] >> 32));
    }
    float* o = out + ((size_t)b * MAXDET + tid) * 5;
    o[0] = v0; o[1] = v1; o[2] = v2; o[3] = v3; o[4] = v4;
  }
  if (tid == 0) out[(size_t)B * MAXDET * 5 + b] = (float)nk;
}

extern "C" void kernel_launch(void* const* d_in, const int* in_sizes, int n_in,
                              void* d_out, int out_size, void* d_ws, size_t ws_size,
                              hipStream_t stream) {
  const float* boxes = (const float*)d_in[0];
  const float* scores = (const float*)d_in[1];
  float* out = (float*)d_out;
  (void)d_ws; (void)ws_size; (void)n_in;
  const int B = out_size / (MAXDET * 5 + 1);  // [B,100,5] + [B]
  postproc_kernel<<<B, NT, 0, stream>>>(boxes, scores, out, B);
}

// Round 11
// 23.846 us; speedup vs baseline: 1.9008x; 1.0666x over previous
//
#include <hip/hip_runtime.h>

#define NT 1024
#define NW 16        // waves per block
#define NH 4         // sub-histograms
#define NBOX 4096
#define NPT 4        // scores per thread
#define MAXDET 100
#define KSEL 192     // top-K selection target (>= 100 + NMS-suppressed margin)
#define CAP 512      // candidate capacity
#define MSMALL 320   // take-all threshold (skip histogram)

typedef unsigned long long u64;
typedef unsigned int u32;
typedef unsigned short u16;

__device__ __forceinline__ float iou_xyxy(float4 a, float4 c) {
  float aa = fmaxf(a.z - a.x, 0.f) * fmaxf(a.w - a.y, 0.f);
  float ca = fmaxf(c.z - c.x, 0.f) * fmaxf(c.w - c.y, 0.f);
  float w = fmaxf(fminf(a.z, c.z) - fmaxf(a.x, c.x), 0.f);
  float h = fmaxf(fminf(a.w, c.w) - fmaxf(a.y, c.y), 0.f);
  float inter = w * h;
  return inter / fmaxf(aa + ca - inter, 1e-9f);
}

__device__ __forceinline__ u64 wave_or64(u64 v) {
#pragma unroll
  for (int d = 1; d < 64; d <<= 1) v |= __shfl_xor(v, d);
  return v;
}

// Exact greedy over 64 slots: rows_mine = suppression row of element `lane`.
__device__ __forceinline__ u64 serial_greedy(u64 rows_mine, u64 removed) {
  u64 keep = 0ull;
  for (int ii = 0; ii < 64; ++ii) {
    u64 row = __shfl(rows_mine, ii);
    if (!((removed >> ii) & 1ull)) { keep |= 1ull << ii; removed |= row; }
  }
  return keep;
}

// 128-wide chunked greedy NMS over sorted (descending) keys.
// LDSBOX: boxes come from cbst[sortedSlot[.]] in LDS; else scattered global bx.
template <bool LDSBOX>
__device__ void run_nms128(const u64* keys, int len, const float4* __restrict__ bx,
                           const u16* sortedSlot, const float4* cbst,
                           float4* chbox, float4* chcw, u64* srowLo, u64* srowHi,
                           u64* crossM, u64* keptkey, float4* keptxy, float4* keptcw,
                           int* p_kept, int tid) {
  const int lane = tid & 63;
  for (int base = 0; base < len; base += 128) {
    if (*p_kept >= MAXDET) break;  // uniform (written before a barrier)
    const int L = min(128, len - base);
    if (tid < 128) {  // ---- stage 128 boxes in one parallel round ----
      if (tid < 2) crossM[tid] = 0ull;
      float4 bb = make_float4(0.f, 0.f, 0.f, 0.f);
      float4 c = make_float4(0.f, 0.f, 0.f, 0.f);
      if (tid < L) {
        if (LDSBOX) {
          c = cbst[sortedSlot[base + tid]];
        } else {
          u64 k = keys[base + tid];
          int orig = NBOX - 1 - (int)(k & 0xFFFFFFFFull);
          c = bx[orig];
        }
        bb = make_float4(c.x - 0.5f * c.z, c.y - 0.5f * c.w,
                         c.x + 0.5f * c.z, c.y + 0.5f * c.w);
      }
      chbox[tid] = bb;
      chcw[tid] = c;
      srowLo[tid] = 0ull;
      srowHi[tid] = 0ull;
    }
    __syncthreads();
    const int kept0 = *p_kept;
    {  // ---- pair tests: 128 rows x 8 slices ----
      int i = tid & 127, slice = tid >> 7;
      if (i < L) {
        float4 a = chbox[i];
        bool hit = false;
        for (int k0 = slice; k0 < kept0 && !hit; k0 += 8)
          if (iou_xyxy(a, keptxy[k0]) > 0.7f) hit = true;
        if (hit) atomicOr(&crossM[i >> 6], 1ull << (i & 63));
        u64 blo = 0ull, bhi = 0ull;
        for (int j = i + 1 + slice; j < L; j += 8)
          if (iou_xyxy(a, chbox[j]) > 0.7f) {
            if (j < 64) blo |= 1ull << j; else bhi |= 1ull << (j - 64);
          }
        if (blo) atomicOr(&srowLo[i], blo);
        if (bhi) atomicOr(&srowHi[i], bhi);
      }
    }
    __syncthreads();
    if (tid < 64) {  // ---- two-half greedy resolution, wave 0 ----
      u64 remL = crossM[0], remH = crossM[1];
      if (L < 64) remL |= ~((1ull << L) - 1ull);
      if (L <= 64) remH = ~0ull;
      else if (L < 128) remH |= ~((1ull << (L - 64)) - 1ull);
      u64 rAlo = srowLo[lane], rAhi = srowHi[lane];  // row of element lane
      u64 rBhi = srowHi[64 + lane];                  // row of element 64+lane
      // half 1
      u64 K1 = ~remL;
      u64 c1 = wave_or64(((K1 >> lane) & 1ull) ? (rAlo & K1) : 0ull);
      u64 keep1 = (c1 == 0ull) ? K1 : serial_greedy(rAlo, remL);
      // cross-suppression from half-1 keepers into half 2
      u64 remH2 = remH | wave_or64(((keep1 >> lane) & 1ull) ? rAhi : 0ull);
      // half 2
      u64 K2 = ~remH2;
      u64 c2 = wave_or64(((K2 >> lane) & 1ull) ? (rBhi & K2) : 0ull);
      u64 keep2 = (c2 == 0ull) ? K2 : serial_greedy(rBhi, remH2);
      // append
      int cnt1 = (int)__popcll(keep1);
      u64 below = (1ull << lane) - 1ull;
      if ((keep1 >> lane) & 1ull) {
        int pos = kept0 + (int)__popcll(keep1 & below);
        if (pos < MAXDET) {
          keptkey[pos] = keys[base + lane];
          keptxy[pos] = chbox[lane];
          keptcw[pos] = chcw[lane];
        }
      }
      if ((keep2 >> lane) & 1ull) {
        int pos = kept0 + cnt1 + (int)__popcll(keep2 & below);
        if (pos < MAXDET) {
          keptkey[pos] = keys[base + 64 + lane];
          keptxy[pos] = chbox[64 + lane];
          keptcw[pos] = chcw[64 + lane];
        }
      }
      if (lane == 0)
        *p_kept = min(MAXDET, kept0 + cnt1 + (int)__popcll(keep2));
    }
    __syncthreads();
  }
}

__global__ __launch_bounds__(NT) void postproc_kernel(
    const float* __restrict__ boxes,   // [B, NBOX, 4] cxcywh
    const float* __restrict__ scores,  // [B, NBOX]
    float* __restrict__ out,           // [B*MAXDET*5] packed, then [B] num
    int B) {
  const int b = blockIdx.x;
  const int tid = threadIdx.x, wid = tid >> 6, lane = tid & 63;

  __shared__ u32 hist[NH][256];    // 4KB sub-histograms (zeroed at entry)
  __shared__ u64 cand[CAP];        // compaction order
  __shared__ u64 sortedCand[CAP];  // rank order (descending)
  __shared__ u16 sortedSlot[CAP];  // rank -> compaction slot
  __shared__ float4 cbst[CAP];     // slot -> cxcywh box (LDS-prefetched)
  __shared__ u64 skey[NBOX];       // 32KB, fallback full sort only
  __shared__ float4 chbox[128];    // chunk xyxy
  __shared__ float4 chcw[128];     // chunk cxcywh
  __shared__ u64 srowLo[128], srowHi[128];
  __shared__ u64 crossM[2];
  __shared__ float4 keptxy[MAXDET];
  __shared__ float4 keptcw[MAXDET];
  __shared__ u64 keptkey[MAXDET];
  __shared__ int s_M, s_C, s_kept, s_ovf, s_byte, s_above, s_bcnt;
  __shared__ int s_minP, s_maxP;

  const float* sc = scores + (size_t)b * NBOX;
  const float4* bx = (const float4*)boxes + (size_t)b * NBOX;

  if (tid == 0) {
    s_M = 0; s_C = 0; s_kept = 0; s_ovf = 0;
    s_minP = 0x7FFFFFFF; s_maxP = -1;
  }
  ((u32*)hist)[tid] = 0u;  // NT == NH*256: full zero, hidden under Phase 1

  // ---- Phase 1: one float4 of scores/thread; keys in regs; M + exp range ----
  u64 key[NPT];
  {
    const int t4 = tid * NPT;
    float4 f0 = *(const float4*)(sc + t4);
    float xs[NPT] = {f0.x, f0.y, f0.z, f0.w};
    int myM = 0, pmin = 0x7FFFFFFF, pmax = -1;
#pragma unroll
    for (int q = 0; q < NPT; ++q) {
      float x = xs[q];
      bool valid = (x > 0.5f);
      u32 bits = __float_as_uint(x);
      key[q] = valid ? (((u64)bits << 32) | (u64)(u32)(NBOX - 1 - (t4 + q))) : 0ull;
      if (valid) {
        int p = (int)(bits >> 23);
        pmin = min(pmin, p); pmax = max(pmax, p); ++myM;
      }
    }
#pragma unroll
    for (int d = 1; d < 64; d <<= 1) {
      myM += __shfl_xor(myM, d);
      pmin = min(pmin, __shfl_xor(pmin, d));
      pmax = max(pmax, __shfl_xor(pmax, d));
    }
    __syncthreads();  // s_* init + hist zero visible
    if (lane == 0) {
      atomicAdd(&s_M, myM);
      atomicMin(&s_minP, pmin);
      atomicMax(&s_maxP, pmax);
    }
  }
  __syncthreads();
  const int M = s_M;
  const bool uniformP = (s_minP == s_maxP);  // all valid share sign+exponent
  bool fullpath = false;
  bool usehist = false;
  u32 thr = 0;

  // ---- Phase 2: selection threshold (1-pass mantissa histogram, 2 barriers) ----
  if (M > MSMALL) {
    if (uniformP) {
      usehist = true;
#pragma unroll
      for (int q = 0; q < NPT; ++q)
        if (key[q]) atomicAdd(&hist[wid >> 2][(u32)(key[q] >> 47) & 255u], 1u);
      __syncthreads();
      if (tid < 64) {  // wave 0: merge sub-hists inline + suffix scan (4 bins/lane)
        int cc[4];
#pragma unroll
        for (int qq = 0; qq < 4; ++qq) {
          int bin = tid * 4 + qq;
          cc[qq] = (int)(hist[0][bin] + hist[1][bin] + hist[2][bin] + hist[3][bin]);
        }
        int tot = cc[0] + cc[1] + cc[2] + cc[3];
        int suf = tot;
#pragma unroll
        for (int d = 1; d < 64; d <<= 1) {
          int o = __shfl_down(suf, d);
          if (tid + d < 64) suf += o;
        }
        if (suf - tot < KSEL && suf >= KSEL) {  // unique crossing lane
          int cum = suf - tot;
          for (int qq = 3; qq >= 0; --qq) {
            if (cum + cc[qq] >= KSEL) { s_byte = tid * 4 + qq; s_above = cum; s_bcnt = cc[qq]; break; }
            cum += cc[qq];
          }
        }
      }
      __syncthreads();
      thr = (u32)s_byte;
      if (s_above + s_bcnt > CAP) fullpath = true;
    } else {
      fullpath = true;
    }
  }

  // ---- Phase 3: compact candidates (wave-aggregated atomics) ----
  if (!fullpath) {
#pragma unroll
    for (int q = 0; q < NPT; ++q) {
      bool take = key[q] && (!usehist || (((u32)(key[q] >> 47) & 255u) >= thr));
      u64 bal = __ballot(take);
      if (bal) {
        int leader = __ffsll((unsigned long long)bal) - 1;
        int basep = 0;
        if (lane == leader) basep = atomicAdd(&s_C, (int)__popcll(bal));
        basep = __shfl(basep, leader);
        if (take) {
          int pos = basep + (int)__popcll(bal & ((1ull << lane) - 1ull));
          if (pos < CAP) cand[pos] = key[q];
          else s_ovf = 1;
        }
      }
    }
  }
  __syncthreads();
  const int C = min(s_C, CAP);
  if (s_ovf) fullpath = true;

  // ---- Phase 4: box prefetch + 4-thread rank-sort + 128-chunk NMS ----
  if (!fullpath && C > 0) {
    // (a) issue scattered box gathers early (latency hides under ranking)
    float4 gbox;
    const bool hasg = (tid < C);
    if (hasg) {
      u64 k = cand[tid];
      int orig = NBOX - 1 - (int)(k & 0xFFFFFFFFull);
      gbox = bx[orig];
    }
    // (b) exact rank: 4 threads per candidate, strided quarters
    {
      int i = tid >> 2, sl = tid & 3;
      if (i < C) {
        u64 ki = cand[i];
        int cnt = 0;
        for (int j = sl; j < C; j += 4) cnt += (cand[j] > ki) ? 1 : 0;
        cnt += __shfl_xor(cnt, 1);  // quad lanes share the same candidate
        cnt += __shfl_xor(cnt, 2);
        if (sl == 0) { sortedCand[cnt] = ki; sortedSlot[cnt] = (u16)i; }
      }
    }
    // (c) land gathered boxes into LDS
    if (hasg) cbst[tid] = gbox;
    __syncthreads();
    run_nms128<true>(sortedCand, C, bx, sortedSlot, cbst, chbox, chcw,
                     srowLo, srowHi, crossM, keptkey, keptxy, keptcw, &s_kept, tid);
  }

  // ---- Phase 5: fully-general fallback (pathological inputs only) ----
  const int kept1 = s_kept;
  const bool selDropped = usehist && (C < M);
  const bool need_full = fullpath || (kept1 < MAXDET && selDropped);
  __syncthreads();
  if (need_full) {
    if (tid == 0) s_kept = 0;
#pragma unroll
    for (int q = 0; q < NPT; ++q) {
      int n = tid * NPT + q;
      skey[n] = key[q] ? key[q] : (u64)(u32)(NBOX - 1 - n);
    }
    __syncthreads();
    for (int k = 2; k <= NBOX; k <<= 1)
      for (int j = k >> 1; j > 0; j >>= 1) {
#pragma clang loop unroll(disable)
        for (int t = tid; t < NBOX; t += NT) {
          int ixj = t ^ j;
          if (ixj > t) {
            u64 a = skey[t], c2 = skey[ixj];
            bool up = (t & k) != 0;
            if (up ? (a > c2) : (a < c2)) { skey[t] = c2; skey[ixj] = a; }
          }
        }
        __syncthreads();
      }
    run_nms128<false>(skey, s_M, bx, sortedSlot, cbst, chbox, chcw,
                      srowLo, srowHi, crossM, keptkey, keptxy, keptcw, &s_kept, tid);
  }

  // ---- Phase 6: outputs (all from LDS; coalesced stores) ----
  const int nk = s_kept;
  if (tid < MAXDET) {
    float v0 = 0.f, v1 = 0.f, v2 = 0.f, v3 = 0.f, v4 = 0.f;
    if (tid < nk) {
      float4 bb = keptcw[tid];  // original cxcywh (staged during NMS)
      v0 = bb.x; v1 = bb.y; v2 = bb.z; v3 = bb.w;
      v4 = __uint_as_float((u32)(keptkey[tid] >> 32));
    }
    float* o = out + ((size_t)b * MAXDET + tid) * 5;
    o[0] = v0; o[1] = v1; o[2] = v2; o[3] = v3; o[4] = v4;
  }
  if (tid == 0) out[(size_t)B * MAXDET * 5 + b] = (float)nk;
}

extern "C" void kernel_launch(void* const* d_in, const int* in_sizes, int n_in,
                              void* d_out, int out_size, void* d_ws, size_t ws_size,
                              hipStream_t stream) {
  const float* boxes = (const float*)d_in[0];
  const float* scores = (const float*)d_in[1];
  float* out = (float*)d_out;
  (void)d_ws; (void)ws_size; (void)n_in;
  const int B = out_size / (MAXDET * 5 + 1);  // [B,100,5] + [B]
  postproc_kernel<<<B, NT, 0, stream>>>(boxes, scores, out, B);
}